// Round 8
// baseline (139.623 us; speedup 1.0000x reference)
//
#include <hip/hip_runtime.h>
#include <math.h>

namespace {
constexpr int Bc = 2, Nc = 5, Cc = 64, Ac = 2, Hc = 128, Wc = 256;
constexpr int SUMN = Bc * Nc;
constexpr int HW = Hc * Wc;
// sigmoid(v) > 0.01  <=>  v > log(0.01/0.99)
constexpr float LOGIT_THRESH = -4.59511985013459f;
constexpr int MASK_BLOCKS = (Bc * HW) / 256;                  // 256
constexpr int FEAT_BLOCKS = (Bc * (Cc / 4) * Hc * (Wc / 4)) / 256;  // 1024

// d_ws layout: int partial[256][10] at byte 0; mask bytes at 10240.
constexpr int MASK_BYTE_OFF = 10240;

typedef float f4v __attribute__((ext_vector_type(4)));

__device__ __forceinline__ f4v load4u(const float* p) {
  f4v r;
  __builtin_memcpy(&r, p, sizeof(r));  // align-4 vector load -> dwordx4
  return r;
}

// owner bits (ego + 2 nearest by |t|^2, ego excluded from top-k) for batch b.
__device__ __forceinline__ unsigned owner_bits(const float* __restrict__ nam, int b) {
  float d2[Nc];
#pragma unroll
  for (int j = 0; j < Nc; ++j) {
    float tx = nam[(size_t)(b * Nc * Nc + j) * 6 + 2];
    float ty = nam[(size_t)(b * Nc * Nc + j) * 6 + 5];
    d2[j] = tx * tx + ty * ty;
  }
  d2[0] = INFINITY;  // ego excluded
  int i1 = 1; float b1 = INFINITY;
#pragma unroll
  for (int j = 0; j < Nc; ++j) if (d2[j] < b1) { b1 = d2[j]; i1 = j; }
  int i2 = 1; float b2 = INFINITY;
#pragma unroll
  for (int j = 0; j < Nc; ++j) if (j != i1 && d2[j] < b2) { b2 = d2[j]; i2 = j; }
  return 1u | (1u << i1) | (1u << i2);
}

// One thread per (b,h,w) pixel: vis/comm/final, packed mask byte,
// exact per-block partial counts (no global atomics).
__global__ void __launch_bounds__(256) k_mask(const float* __restrict__ psm,
                                              const float* __restrict__ nam,
                                              int* __restrict__ partial,
                                              unsigned char* __restrict__ mask) {
  __shared__ int cnt[Nc * 2];
  int tid = threadIdx.x;
  if (tid < Nc * 2) cnt[tid] = 0;
  __syncthreads();

  int t = blockIdx.x * 256 + tid;  // [0, B*HW)
  int b = __builtin_amdgcn_readfirstlane(t >> 15);  // uniform per block
  int h = (t >> 8) & (Hc - 1);
  int w = t & (Wc - 1);
  unsigned own = owner_bits(nam, b);
  float gx = -1.0f + (float)w * (2.0f / (Wc - 1));
  float gy = -1.0f + (float)h * (2.0f / (Hc - 1));
  unsigned m = 0;
#pragma unroll
  for (int j = 0; j < Nc; ++j) {
    int l = b * Nc + j;
    const float* th = nam + (size_t)(b * Nc * Nc + j) * 6;
    float cx = th[0] * gx + th[1] * gy + th[2];
    float cy = th[3] * gx + th[4] * gy + th[5];
    float ix = (cx + 1.0f) * 0.5f * (float)(Wc - 1);
    float iy = (cy + 1.0f) * 0.5f * (float)(Hc - 1);
    int rx = (int)rintf(ix), ry = (int)rintf(iy);
    int vis = (rx >= 0 && rx < Wc && ry >= 0 && ry < Hc) ? 1 : 0;
    int comm = 1;  // agent 0 forced
    if (j != 0) {
      float x0f = floorf(ix), y0f = floorf(iy);
      float fx = ix - x0f, fy = iy - y0f;
      int x0 = (int)x0f, y0 = (int)y0f;
      int x1 = x0 + 1, y1 = y0 + 1;
      bool vx0 = (x0 >= 0) && (x0 < Wc), vx1 = (x1 >= 0) && (x1 < Wc);
      bool vy0 = (y0 >= 0) && (y0 < Hc), vy1 = (y1 >= 0) && (y1 < Hc);
      int cx0 = min(max(x0, 0), Wc - 1), cx1 = min(max(x1, 0), Wc - 1);
      int cy0 = min(max(y0, 0), Hc - 1), cy1 = min(max(y1, 0), Hc - 1);
      int o00 = cy0 * Wc + cx0, o01 = cy0 * Wc + cx1;
      int o10 = cy1 * Wc + cx0, o11 = cy1 * Wc + cx1;
      float w00 = (vy0 && vx0) ? (1.0f - fy) * (1.0f - fx) : 0.0f;
      float w01 = (vy0 && vx1) ? (1.0f - fy) * fx : 0.0f;
      float w10 = (vy1 && vx0) ? fy * (1.0f - fx) : 0.0f;
      float w11 = (vy1 && vx1) ? fy * fx : 0.0f;
      float vmax = -INFINITY;
#pragma unroll
      for (int a = 0; a < Ac; ++a) {
        const float* p = psm + (size_t)(l * Ac + a) * HW;
        float v = p[o00] * w00 + p[o01] * w01 + p[o10] * w10 + p[o11] * w11;
        vmax = fmaxf(vmax, v);
      }
      comm = (vmax > LOGIT_THRESH) ? 1 : 0;
    }
    int fin = comm & (int)((own >> j) & 1u);
    m |= (unsigned)fin << j;
    unsigned long long bv = __ballot(vis != 0);
    unsigned long long bf = __ballot((fin & vis) != 0);
    if ((tid & 63) == 0) {
      atomicAdd(&cnt[j * 2 + 0], (int)__popcll(bv));
      atomicAdd(&cnt[j * 2 + 1], (int)__popcll(bf));
    }
  }
  mask[t] = (unsigned char)m;
  __syncthreads();
  if (tid < Nc * 2) partial[blockIdx.x * (Nc * 2) + tid] = cnt[tid];
}

// One thread per (b, c-quad, h, w-quad): 4 channels x 4 consecutive w.
// Fast path (unit x-step, in-bounds span, uniform row): 2x dwordx4 + 2 scalars
// per (agent,channel) instead of 16 scalar gathers. Scalar fallback otherwise.
// Tail block (blockIdx.x == FEAT_BLOCKS) reduces the rate counters.
__global__ void __launch_bounds__(256) k_feat(const float* __restrict__ x,
                                              const float* __restrict__ nam,
                                              const unsigned char* __restrict__ mask,
                                              const int* __restrict__ partial,
                                              float* __restrict__ out) {
  if (blockIdx.x == FEAT_BLOCKS) {  // rate reduction tail
    int lane = threadIdx.x;
    if (lane < 64) {
      float s = 0.0f;
      for (int l = 0; l < SUMN; ++l) {
        int b = l / Nc, j = l % Nc;
        int vis = 0, num = 0;
#pragma unroll
        for (int k = 0; k < 2; ++k) {  // 128 mask-blocks per b, 2 per lane
          int blk = b * (MASK_BLOCKS / Bc) + lane + 64 * k;
          vis += partial[blk * (Nc * 2) + j * 2 + 0];
          num += partial[blk * (Nc * 2) + j * 2 + 1];
        }
#pragma unroll
        for (int off = 32; off; off >>= 1) {
          vis += __shfl_down(vis, off);
          num += __shfl_down(num, off);
        }
        if (lane == 0) s += (float)num / fmaxf((float)vis, 1.0f);
      }
      if (lane == 0) out[(size_t)Bc * Cc * HW] = s / (float)SUMN;
    }
    return;
  }

  int q = blockIdx.x * 256 + threadIdx.x;  // [0, 262144)
  int w0 = (q & 63) << 2;
  int h = (q >> 6) & (Hc - 1);
  int c4 = (q >> 13) & (Cc / 4 - 1);
  int b = q >> 17;
  int bs = __builtin_amdgcn_readfirstlane(b);  // uniform per block

  unsigned mm4;  // 4 mask bytes for pixels w0..w0+3 (4B aligned)
  __builtin_memcpy(&mm4, mask + (size_t)bs * HW + h * Wc + w0, 4);

  float gy = -1.0f + (float)h * (2.0f / (Hc - 1));
  float best[4][4];  // [channel][pixel]
#pragma unroll
  for (int c = 0; c < 4; ++c)
#pragma unroll
    for (int k = 0; k < 4; ++k) best[c][k] = 0.0f;

#pragma unroll
  for (int j = 0; j < Nc; ++j) {
    if ((mm4 & (0x01010101u << j)) == 0) continue;  // no pixel uses agent j
    int l = bs * Nc + j;
    const float* th = nam + (size_t)(bs * Nc * Nc + j) * 6;
    float t00 = th[0], t01 = th[1], t02 = th[2];
    float t10 = th[3], t11 = th[4], t12 = th[5];

    float ix[4], iy[4], fx[4], fy[4];
    int x0i[4], y0i[4];
#pragma unroll
    for (int k = 0; k < 4; ++k) {
      float gx = -1.0f + (float)(w0 + k) * (2.0f / (Wc - 1));
      float cx = t00 * gx + t01 * gy + t02;
      float cy = t10 * gx + t11 * gy + t12;
      ix[k] = (cx + 1.0f) * 0.5f * (float)(Wc - 1);
      iy[k] = (cy + 1.0f) * 0.5f * (float)(Hc - 1);
      float x0f = floorf(ix[k]), y0f = floorf(iy[k]);
      fx[k] = ix[k] - x0f; fy[k] = iy[k] - y0f;
      x0i[k] = (int)x0f; y0i[k] = (int)y0f;
    }
    int X0 = x0i[0], Y0 = y0i[0];
    bool fast = (x0i[1] == X0 + 1) && (x0i[2] == X0 + 2) && (x0i[3] == X0 + 3) &&
                (y0i[1] == Y0) && (y0i[2] == Y0) && (y0i[3] == Y0) &&
                (X0 >= 0) && (X0 + 4 < Wc);
    const float* xb = x + (size_t)(l * Cc + c4 * 4) * HW;

    if (fast) {
      bool vy0 = (Y0 >= 0) && (Y0 < Hc), vy1 = (Y0 + 1 >= 0) && (Y0 + 1 < Hc);
      int cy0 = min(max(Y0, 0), Hc - 1), cy1 = min(max(Y0 + 1, 0), Hc - 1);
      int r0off = cy0 * Wc + X0, r1off = cy1 * Wc + X0;
      float wy0[4], wy1[4];
#pragma unroll
      for (int k = 0; k < 4; ++k) {
        wy0[k] = vy0 ? (1.0f - fy[k]) : 0.0f;
        wy1[k] = vy1 ? fy[k] : 0.0f;
      }
      const float* p = xb;
#pragma unroll
      for (int c = 0; c < 4; ++c) {
        f4v a0 = load4u(p + r0off); float a0e = p[r0off + 4];
        f4v a1 = load4u(p + r1off); float a1e = p[r1off + 4];
        float r0[5] = {a0.x, a0.y, a0.z, a0.w, a0e};
        float r1[5] = {a1.x, a1.y, a1.z, a1.w, a1e};
#pragma unroll
        for (int k = 0; k < 4; ++k) {
          float val = wy0[k] * (r0[k] * (1.0f - fx[k]) + r0[k + 1] * fx[k]) +
                      wy1[k] * (r1[k] * (1.0f - fx[k]) + r1[k + 1] * fx[k]);
          val = ((mm4 >> (8 * k + j)) & 1u) ? val : 0.0f;
          best[c][k] = fmaxf(best[c][k], val);
        }
        p += HW;
      }
    } else {
#pragma unroll
      for (int k = 0; k < 4; ++k) {
        if (((mm4 >> (8 * k + j)) & 1u) == 0) continue;
        int x0 = x0i[k], y0 = y0i[k], x1 = x0 + 1, y1 = y0 + 1;
        bool vx0 = (x0 >= 0) && (x0 < Wc), vx1 = (x1 >= 0) && (x1 < Wc);
        bool vy0 = (y0 >= 0) && (y0 < Hc), vy1 = (y1 >= 0) && (y1 < Hc);
        int cx0 = min(max(x0, 0), Wc - 1), cx1 = min(max(x1, 0), Wc - 1);
        int cy0 = min(max(y0, 0), Hc - 1), cy1 = min(max(y1, 0), Hc - 1);
        int o00 = cy0 * Wc + cx0, o01 = cy0 * Wc + cx1;
        int o10 = cy1 * Wc + cx0, o11 = cy1 * Wc + cx1;
        float w00 = (vy0 && vx0) ? (1.0f - fy[k]) * (1.0f - fx[k]) : 0.0f;
        float w01 = (vy0 && vx1) ? (1.0f - fy[k]) * fx[k] : 0.0f;
        float w10 = (vy1 && vx0) ? fy[k] * (1.0f - fx[k]) : 0.0f;
        float w11 = (vy1 && vx1) ? fy[k] * fx[k] : 0.0f;
        const float* p = xb;
#pragma unroll
        for (int c = 0; c < 4; ++c) {
          float val = p[o00] * w00 + p[o01] * w01 + p[o10] * w10 + p[o11] * w11;
          best[c][k] = fmaxf(best[c][k], val);
          p += HW;
        }
      }
    }
  }

  size_t obase = (size_t)(bs * Cc + c4 * 4) * HW + h * Wc + w0;
#pragma unroll
  for (int c = 0; c < 4; ++c) {
    f4v v = {best[c][0], best[c][1], best[c][2], best[c][3]};
    __builtin_nontemporal_store(v, (f4v*)(out + obase + (size_t)c * HW));
  }
}

}  // namespace

extern "C" void kernel_launch(void* const* d_in, const int* in_sizes, int n_in,
                              void* d_out, int out_size, void* d_ws, size_t ws_size,
                              hipStream_t stream) {
  const float* x = (const float*)d_in[0];
  const float* psm = (const float*)d_in[1];
  const float* nam = (const float*)d_in[2];
  // d_in[3] = record_len (compile-time constant Nc)
  float* out = (float*)d_out;
  int* partial = (int*)d_ws;
  unsigned char* mask = (unsigned char*)d_ws + MASK_BYTE_OFF;

  hipLaunchKernelGGL(k_mask, dim3(MASK_BLOCKS), dim3(256), 0, stream, psm, nam, partial, mask);
  hipLaunchKernelGGL(k_feat, dim3(FEAT_BLOCKS + 1), dim3(256), 0, stream, x, nam, mask, partial,
                     out);
}